// Round 3
// baseline (625.077 us; speedup 1.0000x reference)
//
#include <hip/hip_runtime.h>
#include <stdint.h>

// MS-SSIM + L1 fused loss, MI355X.
// R2 change: kill register spills structurally.
//  - Gaussian weights are compile-time constexpr tables (no VGPR/expf cost).
//  - do_sigma reordered: keep only A=mux*muy, B=mux^2+muy^2 across passes;
//    fold l^3 into PIcs (lM array dropped).
//  - __launch_bounds__(512,2): allow up to 256 VGPR so the allocator never
//    spills (R0/R1 spilled 400-900MB/launch to scratch -> HBM bound).

#define TILE 64
#define HALO 16
#define HA   96      // halo extent (TILE + 2*HALO)
#define XSTR 96      // ushort stride of Xs/Ys rows
#define HSTR 68      // float stride of H-plane rows
#define NTHREADS 512

#define C1c 1.0e-4f  // (0.01*DR)^2
#define C2c 9.0e-4f  // (0.03*DR)^2

// ---------- compile-time Gaussian weights ----------
constexpr double cexp(double x) {
  if (x < -700.0) return 0.0;
  const double ln2 = 0.6931471805599453;
  const double inv_ln2 = 1.4426950408889634;
  double kd = x * inv_ln2;
  long long k = (long long)(kd + (kd >= 0 ? 0.5 : -0.5));
  double r = x - (double)k * ln2;
  double t = 1.0, s = 1.0;
  for (int i = 1; i <= 22; ++i) { t *= r / (double)i; s += t; }
  double p = 1.0;
  double base = (k >= 0) ? 2.0 : 0.5;
  long long n = (k >= 0) ? k : -k;
  while (n) { if (n & 1) p *= base; base *= base; n >>= 1; }
  return s * p;
}

template<int R>
struct WTab {
  float w[2 * R + 1];
  constexpr WTab(double sigma) : w() {
    double inv = 1.0 / (2.0 * sigma * sigma);
    double s = 0.0;
    for (int k = -16; k <= 16; ++k) s += cexp(-(double)(k * k) * inv);
    for (int k = 0; k <= 2 * R; ++k) {
      int d = k - R;
      w[k] = (float)(cexp(-(double)(d * d) * inv) / s);
    }
  }
};

constexpr WTab<4>  W05(0.5);
constexpr WTab<7>  W10(1.0);
constexpr WTab<13> W20(2.0);
constexpr WTab<16> W40(4.0);
constexpr WTab<16> W80(8.0);

// ---------- helpers ----------
__device__ __forceinline__ float bf2f(unsigned short h) {
  union { unsigned int u; float f; } c; c.u = ((unsigned int)h) << 16; return c.f;
}
__device__ __forceinline__ unsigned short f2bf(float f) {
  union { float f; unsigned int u; } c; c.f = f;
  unsigned int r = (c.u + 0x7FFFu + ((c.u >> 16) & 1u)) >> 16;
  return (unsigned short)r;
}

__device__ __forceinline__ void unpack8(uint4 u, float* v) {
  union { unsigned int u32; float f; } c;
  c.u32 = u.x << 16;         v[0] = c.f;
  c.u32 = u.x & 0xFFFF0000u; v[1] = c.f;
  c.u32 = u.y << 16;         v[2] = c.f;
  c.u32 = u.y & 0xFFFF0000u; v[3] = c.f;
  c.u32 = u.z << 16;         v[4] = c.f;
  c.u32 = u.z & 0xFFFF0000u; v[5] = c.f;
  c.u32 = u.w << 16;         v[6] = c.f;
  c.u32 = u.w & 0xFFFF0000u; v[7] = c.f;
}

// Horizontal pass, streaming form. Q: 0=x, 1=y, 2=x*x, 3=y*y, 4=x*y, 5=|x-y|
template<int R, int Q>
__device__ __forceinline__ void hpass(const unsigned short* __restrict__ Xs,
                                      const unsigned short* __restrict__ Ys,
                                      float* __restrict__ Hs,
                                      const float* __restrict__ w, int tid) {
  constexpr int START = HALO - R;          // leftmost rel. input col for colgroup 0
  constexpr int ABASE = START & ~7;        // align to 8 bf16 (16B)
  constexpr int OFF   = START - ABASE;
  constexpr int WIN   = 2 * R + 8;         // window floats per 8 outputs
  constexpr int NV    = (OFF + WIN + 7) >> 3;
  constexpr int ROWS  = TILE + 2 * R;      // rows the V-pass will consume
  constexpr int NS    = 8 * ROWS;          // strips (8 colgroups x ROWS)
  static_assert(OFF + 7 + 2 * R <= NV * 8 - 1, "window fits");
  for (int s = tid; s < NS; s += NTHREADS) {
    const int g = s & 7;
    const int r = (s >> 3) + (HALO - R);
    const int base = r * XSTR + ABASE + g * 8;
    const uint4* qx = (const uint4*)(Xs + base);
    const uint4* qy = (const uint4*)(Ys + base);
    float acc[8] = {0.f,0.f,0.f,0.f,0.f,0.f,0.f,0.f};
    #pragma unroll
    for (int j = 0; j < NV; ++j) {
      float val[8];
      if (Q == 0) {
        unpack8(qx[j], val);
      } else if (Q == 1) {
        unpack8(qy[j], val);
      } else if (Q == 2) {
        unpack8(qx[j], val);
        #pragma unroll
        for (int jj = 0; jj < 8; ++jj) val[jj] *= val[jj];
      } else if (Q == 3) {
        unpack8(qy[j], val);
        #pragma unroll
        for (int jj = 0; jj < 8; ++jj) val[jj] *= val[jj];
      } else {
        float vy[8];
        unpack8(qx[j], val);
        unpack8(qy[j], vy);
        if (Q == 4) {
          #pragma unroll
          for (int jj = 0; jj < 8; ++jj) val[jj] *= vy[jj];
        } else {
          #pragma unroll
          for (int jj = 0; jj < 8; ++jj) val[jj] = fabsf(val[jj] - vy[jj]);
        }
      }
      #pragma unroll
      for (int jj = 0; jj < 8; ++jj) {
        const int k = j * 8 + jj;        // window index (compile-time)
        #pragma unroll
        for (int o = 0; o < 8; ++o) {
          const int wi = k - OFF - o;    // tap index (compile-time)
          if (wi >= 0 && wi <= 2 * R)
            acc[o] = fmaf(w[wi], val[jj], acc[o]);
        }
      }
    }
    float4* dst = (float4*)(Hs + r * HSTR + g * 8);
    dst[0] = make_float4(acc[0], acc[1], acc[2], acc[3]);
    dst[1] = make_float4(acc[4], acc[5], acc[6], acc[7]);
  }
}

template<int R>
__device__ __forceinline__ void vpass(const float* __restrict__ Hs,
                                      const float* __restrict__ w,
                                      int tid, float* __restrict__ out) {
  const int c  = tid & 63;
  const int rg = tid >> 6;
  const int rbase = rg * 8 + HALO - R;
  float acc[8] = {0.f,0.f,0.f,0.f,0.f,0.f,0.f,0.f};
  #pragma unroll
  for (int i = 0; i < 2 * R + 8; ++i) {
    float hv = Hs[(rbase + i) * HSTR + c];
    #pragma unroll
    for (int o = 0; o < 8; ++o) {
      if (i - o >= 0 && i - o <= 2 * R)
        acc[o] = fmaf(w[i - o], hv, acc[o]);
    }
  }
  #pragma unroll
  for (int o = 0; o < 8; ++o) out[o] = acc[o];
}

// One full (sigma) SSIM pass; keeps only A=mux*muy, B=mux^2+muy^2 across
// sub-passes; folds l^3 into PIcs when LAST.
template<int R, int MULT, bool LAST>
__device__ __forceinline__ void do_sigma(const float* __restrict__ w,
                                         const unsigned short* Xs,
                                         const unsigned short* Ys,
                                         float* Hs, int tid, float* PIcs) {
  float A[8], B[8], S[8], t[8];
  // mux
  hpass<R,0>(Xs, Ys, Hs, w, tid); __syncthreads(); vpass<R>(Hs, w, tid, t); __syncthreads();
  #pragma unroll
  for (int i = 0; i < 8; ++i) { A[i] = t[i]; }
  // muy
  hpass<R,1>(Xs, Ys, Hs, w, tid); __syncthreads(); vpass<R>(Hs, w, tid, t); __syncthreads();
  #pragma unroll
  for (int i = 0; i < 8; ++i) {
    const float mux = A[i], muy = t[i];
    A[i] = mux * muy;
    B[i] = mux * mux + muy * muy;
  }
  // E[x^2]
  hpass<R,2>(Xs, Ys, Hs, w, tid); __syncthreads(); vpass<R>(Hs, w, tid, S); __syncthreads();
  // E[y^2] -> S = sx2 + sy2
  hpass<R,3>(Xs, Ys, Hs, w, tid); __syncthreads(); vpass<R>(Hs, w, tid, t); __syncthreads();
  #pragma unroll
  for (int i = 0; i < 8; ++i) S[i] = S[i] + t[i] - B[i];
  // E[xy] -> cs
  hpass<R,4>(Xs, Ys, Hs, w, tid); __syncthreads(); vpass<R>(Hs, w, tid, t); __syncthreads();
  #pragma unroll
  for (int i = 0; i < 8; ++i) {
    const float sxy = t[i] - A[i];
    const float cs = (2.f * sxy + C2c) / (S[i] + C2c);
    float p = cs;
    if (MULT >= 2) p *= cs;
    if (MULT >= 3) p *= cs;
    if (LAST) {
      const float l = (2.f * A[i] + C1c) / (B[i] + C1c);
      p *= l * l * l;
    }
    PIcs[i] *= p;
  }
}

template<int R>
__device__ __forceinline__ void do_l1(const float* __restrict__ w,
                                      const unsigned short* Xs,
                                      const unsigned short* Ys,
                                      float* Hs, int tid, float* gl1) {
  float rr[8];
  hpass<R,5>(Xs, Ys, Hs, w, tid); __syncthreads(); vpass<R>(Hs, w, tid, rr); __syncthreads();
  #pragma unroll
  for (int i = 0; i < 8; ++i) gl1[i] += rr[i];
}

__global__ __launch_bounds__(NTHREADS, 2)
void msssim_fused_kernel(const float* __restrict__ x, const float* __restrict__ y,
                         float* __restrict__ partials) {
  __shared__ unsigned short Xs[HA * XSTR];
  __shared__ unsigned short Ys[HA * XSTR];
  __shared__ float Hs[HA * HSTR];
  __shared__ float red[16];

  const int tid = threadIdx.x;
  const int bx = blockIdx.x, by = blockIdx.y, b = blockIdx.z;
  const int y0 = by * TILE - HALO;
  const int x0 = bx * TILE - HALO;

  float PIcs[8], gl1[8];
  #pragma unroll
  for (int i = 0; i < 8; ++i) { PIcs[i] = 1.f; gl1[i] = 0.f; }
  float absacc = 0.f;

  for (int ch = 0; ch < 3; ++ch) {
    __syncthreads();   // protect Xs/Ys from prior channel readers
    const float* __restrict__ xs = x + (size_t)(b * 3 + ch) * 512 * 512;
    const float* __restrict__ ys = y + (size_t)(b * 3 + ch) * 512 * 512;
    for (int idx = tid; idx < HA * HA; idx += NTHREADS) {
      const int r  = idx / HA;
      const int cc = idx - r * HA;
      const int gy = y0 + r, gx = x0 + cc;
      const bool ok = (gy >= 0) && (gy < 512) && (gx >= 0) && (gx < 512);
      float xv = 0.f, yv = 0.f;
      if (ok) { xv = xs[gy * 512 + gx] * 0.5f + 0.5f; yv = ys[gy * 512 + gx] * 0.5f + 0.5f; }
      Xs[idx] = ok ? f2bf(xv) : (unsigned short)0;
      Ys[idx] = ok ? f2bf(yv) : (unsigned short)0;
    }
    __syncthreads();

    { // plain per-pixel |x-y| for gen-loss L1 (denormalized x,y)
      const int c = tid & 63, rg = tid >> 6;
      #pragma unroll
      for (int i = 0; i < 8; ++i) {
        const int hidx = (HALO + rg * 8 + i) * XSTR + HALO + c;
        absacc += fabsf(bf2f(Xs[hidx]) - bf2f(Ys[hidx]));
      }
    }

    if (ch == 0) {
      do_sigma<4, 3, false>(W05.w, Xs, Ys, Hs, tid, PIcs);
      do_sigma<7, 2, false>(W10.w, Xs, Ys, Hs, tid, PIcs);
      do_l1<16>(W80.w, Xs, Ys, Hs, tid, gl1);
    } else if (ch == 1) {
      do_sigma<7, 1, false>(W10.w, Xs, Ys, Hs, tid, PIcs);
      do_sigma<13, 3, false>(W20.w, Xs, Ys, Hs, tid, PIcs);
      do_sigma<16, 1, false>(W40.w, Xs, Ys, Hs, tid, PIcs);
      do_l1<16>(W80.w, Xs, Ys, Hs, tid, gl1);
    } else {
      do_sigma<16, 2, false>(W40.w, Xs, Ys, Hs, tid, PIcs);
      do_sigma<16, 3, true>(W80.w, Xs, Ys, Hs, tid, PIcs);
      do_l1<16>(W80.w, Xs, Ys, Hs, tid, gl1);
    }
  }

  float mixsum = 0.f;
  #pragma unroll
  for (int i = 0; i < 8; ++i) {
    const float ssim = 1.f - PIcs[i];
    mixsum += 200.f * (0.025f * ssim + 0.975f * (gl1[i] * (1.f / 3.f)));
  }

  // block reduction of mixsum and absacc
  #pragma unroll
  for (int off = 32; off > 0; off >>= 1) {
    mixsum += __shfl_down(mixsum, off);
    absacc += __shfl_down(absacc, off);
  }
  const int wave = tid >> 6, lane = tid & 63;
  if (lane == 0) { red[wave] = mixsum; red[8 + wave] = absacc; }
  __syncthreads();
  if (tid == 0) {
    float m = 0.f, a = 0.f;
    #pragma unroll
    for (int i = 0; i < 8; ++i) { m += red[i]; a += red[8 + i]; }
    const int blk = (b * 8 + by) * 8 + bx;
    partials[2 * blk + 0] = m;
    partials[2 * blk + 1] = a;
  }
}

__global__ __launch_bounds__(512)
void msssim_final_kernel(const float* __restrict__ partials,
                         const float* __restrict__ disc,
                         float* __restrict__ out) {
  __shared__ float red[24];
  const int tid = threadIdx.x;
  float m = 0.f, a = 0.f, d2 = 0.f;
  { // exactly one partial pair per thread (512 blocks, 512 threads)
    m = partials[2 * tid + 0];
    a = partials[2 * tid + 1];
  }
  for (int i = tid; i < 8 * 62 * 62; i += 512) {
    const float d = disc[i] - 1.f;
    d2 = fmaf(d, d, d2);
  }
  #pragma unroll
  for (int off = 32; off > 0; off >>= 1) {
    m  += __shfl_down(m, off);
    a  += __shfl_down(a, off);
    d2 += __shfl_down(d2, off);
  }
  const int wave = tid >> 6, lane = tid & 63;
  if (lane == 0) { red[wave] = m; red[8 + wave] = a; red[16 + wave] = d2; }
  __syncthreads();
  if (tid == 0) {
    float sm = 0.f, sa = 0.f, sd = 0.f;
    #pragma unroll
    for (int i = 0; i < 8; ++i) { sm += red[i]; sa += red[8 + i]; sd += red[16 + i]; }
    const float mix_mean  = sm / (8.f * 512.f * 512.f);
    const float abs_mean  = sa / (8.f * 3.f * 512.f * 512.f);
    const float disc_mean = sd / (8.f * 62.f * 62.f);
    out[0] = 0.5f * (mix_mean + 100.f * abs_mean + disc_mean);
  }
}

extern "C" void kernel_launch(void* const* d_in, const int* in_sizes, int n_in,
                              void* d_out, int out_size, void* d_ws, size_t ws_size,
                              hipStream_t stream) {
  const float* x    = (const float*)d_in[0];
  const float* y    = (const float*)d_in[1];
  const float* disc = (const float*)d_in[2];
  // d_in[3] = g_masks (unused: weights are recomputed exactly at compile time)
  float* partials = (float*)d_ws;   // 512 * 2 floats, fully overwritten each call
  dim3 grid(8, 8, 8);
  msssim_fused_kernel<<<grid, NTHREADS, 0, stream>>>(x, y, partials);
  msssim_final_kernel<<<1, 512, 0, stream>>>(partials, disc, (float*)d_out);
}